// Round 2
// baseline (181.726 us; speedup 1.0000x reference)
//
#include <hip/hip_runtime.h>

#define DMD 128
#define NV 64
#define BB 2
#define SQ 512
#define NBN 128                 // BB*NV
#define ASCALE 0.08838834764831845f   // 128^-0.5

// workspace layout (float offsets)
#define WS_XE  0                       // [NBN][DMD]
#define WS_PW  (WS_XE + NBN*DMD)       // [BB][2]
#define WS_VEC (WS_PW + 4)             // 9*128: Aq,Cq,Pq,Ak,Ck,Pk,Av,Cv,Pv
#define WS_OB  (WS_VEC + 9*DMD)        // [NBN][DMD][DMD] blended o

// ---------------- xe[bn][t] = sum_s x[b,s,n]*W_emb[s,t] + b_emb[t] ----------------
__global__ __launch_bounds__(128) void k_xe(const float* __restrict__ x,
                                            const float* __restrict__ W_emb,
                                            const float* __restrict__ b_emb,
                                            float* __restrict__ ws) {
    int bn = blockIdx.x;
    int b = bn >> 6, n = bn & 63;
    int t = threadIdx.x;
    __shared__ float xs[SQ];
    for (int s = t; s < SQ; s += 128) xs[s] = x[(b * SQ + s) * NV + n];
    __syncthreads();
    float acc = b_emb[t];
    for (int s = 0; s < SQ; ++s) acc = fmaf(xs[s], W_emb[s * DMD + t], acc);
    ws[WS_XE + bn * DMD + t] = acc;
}

// ---------------- period weights: table-based DFT at f1,f2 -> softmax ----------------
__global__ __launch_bounds__(128) void k_pw(const int* __restrict__ f1p,
                                            const int* __restrict__ f2p,
                                            float* __restrict__ ws) {
    int b = blockIdx.x;        // 2 blocks
    int tid = threadIdx.x;     // 128 = 64 n x 2 freqs
    __shared__ float ct[DMD], st[DMD];
    __shared__ float a2[2];
    float ang = (float)tid * 0.04908738521234052f;   // 2*pi/128
    ct[tid] = cosf(ang);
    st[tid] = sinf(ang);
    __syncthreads();
    int k = tid >> 6;          // freq slot (one wave each)
    int n = tid & 63;
    int f = k ? f2p[0] : f1p[0];
    const float* xr = ws + WS_XE + (b * NV + n) * DMD;
    float re = 0.f, im = 0.f;
    for (int t = 0; t < DMD; ++t) {
        int ph = (f * t) & (DMD - 1);
        float v = xr[t];
        re = fmaf(v, ct[ph], re);
        im = fmaf(v, st[ph], im);
    }
    float amp = sqrtf(re * re + im * im);
    for (int off = 32; off > 0; off >>= 1) amp += __shfl_down(amp, off);
    if (n == 0) a2[k] = amp * (1.0f / NV);
    __syncthreads();
    if (tid == 0) {
        float m = fmaxf(a2[0], a2[1]);
        float e0 = expf(a2[0] - m), e1 = expf(a2[1] - m);
        float inv = 1.0f / (e0 + e1);
        ws[WS_PW + b * 2 + 0] = e0 * inv;
        ws[WS_PW + b * 2 + 1] = e1 * inv;
    }
}

// ---------------- projected rank-1 vectors ----------------
__global__ __launch_bounds__(128) void k_vec(const float* __restrict__ Wel, const float* __restrict__ bel,
                                             const float* __restrict__ W_start, const float* __restrict__ b_start,
                                             const float* __restrict__ Wq, const float* __restrict__ bq,
                                             const float* __restrict__ Wk, const float* __restrict__ bk,
                                             const float* __restrict__ Wv, const float* __restrict__ bv,
                                             float* __restrict__ ws) {
    int e = threadIdx.x;
    __shared__ float A[DMD], C[DMD], BL[DMD];
    float a = 0.f, c = 0.f;
    for (int d = 0; d < DMD; ++d) {
        float w = Wel[e * DMD + d];
        a = fmaf(w, W_start[d], a);
        c = fmaf(w, b_start[d], c);
    }
    A[e] = a;
    C[e] = c + bel[e];
    BL[e] = bel[e];
    __syncthreads();
    float aq = 0, cq = 0, pq = 0, ak = 0, ck = 0, pk = 0, av = 0, cv = 0, pv = 0;
    for (int d = 0; d < DMD; ++d) {
        float Ad = A[d], Cd = C[d], Bd = BL[d];
        float wq = Wq[e * DMD + d], wk = Wk[e * DMD + d], wv = Wv[e * DMD + d];
        aq = fmaf(wq, Ad, aq); cq = fmaf(wq, Cd, cq); pq = fmaf(wq, Bd, pq);
        ak = fmaf(wk, Ad, ak); ck = fmaf(wk, Cd, ck); pk = fmaf(wk, Bd, pk);
        av = fmaf(wv, Ad, av); cv = fmaf(wv, Cd, cv); pv = fmaf(wv, Bd, pv);
    }
    float* V = ws + WS_VEC;
    V[0 * DMD + e] = aq; V[1 * DMD + e] = cq + bq[e]; V[2 * DMD + e] = pq + bq[e];
    V[3 * DMD + e] = ak; V[4 * DMD + e] = ck + bk[e]; V[5 * DMD + e] = pk + bk[e];
    V[6 * DMD + e] = av; V[7 * DMD + e] = cv + bv[e]; V[8 * DMD + e] = pv + bv[e];
}

// ---------------- attention, both branches fused, W-matrix cached in LDS ----------------
__global__ __launch_bounds__(128) void k_attn(const int* __restrict__ f1p,
                                              const int* __restrict__ f2p,
                                              float* __restrict__ ws) {
    int bn = blockIdx.y;
    int b = bn >> 6;
    int echunk = blockIdx.x;           // 16 chunks of 8 e's
    int tid = threadIdx.x;             // 128

    __shared__ float xs[DMD];
    __shared__ float U[DMD];
    __shared__ float aS[DMD], bK[DMD];
    __shared__ float g[4160];          // rows stride P+1, Prows<=64, P<=64 when used
    __shared__ float Wm[4160];
    __shared__ float pm[2][64], ps[2][64];

    xs[tid] = ws[WS_XE + bn * DMD + tid];
    int f1v = f1p[0], f2v = f2p[0];
    const float* V = ws + WS_VEC;
    float pw0 = ws[WS_PW + b * 2 + 0];
    float pw1 = ws[WS_PW + b * 2 + 1];
    __syncthreads();

    for (int ec = 0; ec < 8; ++ec) {
        int e = echunk * 8 + ec;
        float Aq = V[0 * DMD + e], Cq = V[1 * DMD + e], Pq = V[2 * DMD + e];
        float Ak = V[3 * DMD + e], Ck = V[4 * DMD + e], Pk = V[5 * DMD + e];
        float Av = V[6 * DMD + e], Cv = V[7 * DMD + e], Pv = V[8 * DMD + e];
        float acc = 0.f;

        for (int br = 0; br < 2; ++br) {
            int f = br ? f2v : f1v;
            int P = DMD / f;
            int pn = (DMD + P - 1) / P;
            int r = DMD - (pn - 1) * P;
            int GP = P + 1;
            int Prows = (DMD + pn - 1) / pn;
            float pwv = br ? pw1 : pw0;
            float c1 = ASCALE * Aq * Ak, c2 = ASCALE * Aq * Ck;
            float c3 = ASCALE * Cq * Ak, c4 = ASCALE * (float)(pn - 1) * Cq * Ck;

            __syncthreads();   // S1: previous iteration's readers done
            if (pn >= 2) {
                if (tid < P) {
                    float s = 0.f;
                    for (int p = 0; p < pn - 1; ++p) s += xs[p * P + tid];
                    U[tid] = s;
                    int t = (pn - 1) * P + tid;
                    aS[tid] = ASCALE * ((tid < r) ? fmaf(xs[t], Aq, Cq) : Pq);
                    bK[tid] = (tid < r) ? fmaf(xs[t], Ak, Ck) : Pk;
                }
                for (int idx = tid; idx < Prows * P; idx += 128) {
                    int gi = idx / P;
                    int gj = idx - gi * P;
                    float s = 0.f;
                    for (int p = 0; p < pn - 1; ++p) s = fmaf(xs[p * P + gi], xs[p * P + gj], s);
                    g[gi * GP + gj] = s;
                }
                __syncthreads();   // S2: fills ready

                // pass A: S -> Wm, row max (2 halves per row)
                int i = tid & 63, half = tid >> 6;
                int h1 = (P + 1) >> 1;
                int j0 = half ? h1 : 0, j1 = half ? P : h1;
                bool act = (i < Prows);
                if (act) {
                    float h = fmaf(c2, U[i], c4);
                    float asi = aS[i];
                    int row = i * GP;
                    float mpart = -1e30f;
                    for (int j = j0; j < j1; ++j) {
                        float S = fmaf(c1, g[row + j], fmaf(c3, U[j], fmaf(asi, bK[j], h)));
                        Wm[row + j] = S;
                        mpart = fmaxf(mpart, S);
                    }
                    pm[half][i] = mpart;
                }
                __syncthreads();   // S3
                if (act) {
                    float m = fmaxf(pm[0][i], pm[1][i]);
                    int row = i * GP;
                    float lpart = 0.f;
                    for (int j = j0; j < j1; ++j) {
                        float w = __expf(Wm[row + j] - m);
                        Wm[row + j] = w;
                        lpart += w;
                    }
                    ps[half][i] = lpart;
                }
                __syncthreads();   // S4

                // PV: one output per thread
                int mo = tid;
                int i2 = mo / pn;
                int p = mo - i2 * pn;
                float li = 1.0f / (ps[0][i2] + ps[1][i2]);
                int limit = (p == pn - 1) ? r : P;
                int row = i2 * GP, base = p * P;
                float accx = 0.f, accs = 0.f;
                for (int j = 0; j < limit; ++j) {
                    float w = Wm[row + j];
                    accx = fmaf(w, xs[base + j], accx);
                    accs += w;
                }
                float sl = accs * li;
                float o = fmaf(Av, accx * li, fmaf(Cv, sl, Pv * (1.0f - sl)));
                acc = fmaf(pwv, o, acc);
            } else {
                // pn == 1 (f == 1, P == 128): S[i,j] = aS[i]*bK[j], rank-1, no padding
                aS[tid] = ASCALE * fmaf(xs[tid], Aq, Cq);
                bK[tid] = fmaf(xs[tid], Ak, Ck);
                __syncthreads();   // S2
                float asi = aS[tid];
                float m = -1e30f;
                for (int j = 0; j < DMD; ++j) m = fmaxf(m, asi * bK[j]);
                float l = 0.f, accx = 0.f;
                for (int j = 0; j < DMD; ++j) {
                    float w = __expf(asi * bK[j] - m);
                    l += w;
                    accx = fmaf(w, xs[j], accx);
                }
                float o = fmaf(Av, accx / l, Cv);
                acc = fmaf(pwv, o, acc);
            }
        }
        ws[WS_OB + (bn * DMD + e) * DMD + tid] = acc;
    }
}

// ---------------- out[bn][e][h] = sum_m oblend[bn][e][m]*Wo[h][m] + bo[h] ----------------
__global__ __launch_bounds__(256) void k_out(const float* __restrict__ Wo,
                                             const float* __restrict__ bo,
                                             const float* __restrict__ ws,
                                             float* __restrict__ out) {
    int blk = blockIdx.x;          // 256 = 64 bn-pairs * 4 e-quarters
    int bn0 = (blk >> 2) * 2;
    int e0  = (blk & 3) * 32;
    int tid = threadIdx.x;
    __shared__ __align__(16) float WT[DMD * 132];   // WT[m*132+h] = Wo[h][m]
    __shared__ float orow[2][32][DMD];
    for (int idx = tid; idx < DMD * DMD; idx += 256) {
        int h = idx >> 7, m = idx & 127;
        WT[m * 132 + h] = Wo[idx];
    }
    for (int idx = tid; idx < 2 * 32 * DMD; idx += 256) {
        int bnl = idx >> 12;
        int rem = idx & 4095;
        int e = rem >> 7, m = rem & 127;
        orow[bnl][e][m] = ws[WS_OB + ((bn0 + bnl) * DMD + e0 + e) * DMD + m];
    }
    __syncthreads();
    int hg = tid & 31;
    int eg = tid >> 5;             // 0..7
    int h0 = hg * 4;
    float acc[2][4][4];
    #pragma unroll
    for (int a = 0; a < 2; ++a)
        #pragma unroll
        for (int c = 0; c < 4; ++c)
            #pragma unroll
            for (int d = 0; d < 4; ++d) acc[a][c][d] = 0.f;

    #pragma unroll 2
    for (int m = 0; m < DMD; ++m) {
        const float4 wv = *reinterpret_cast<const float4*>(&WT[m * 132 + h0]);
        #pragma unroll
        for (int bnl = 0; bnl < 2; ++bnl) {
            #pragma unroll
            for (int el = 0; el < 4; ++el) {
                float a = orow[bnl][eg * 4 + el][m];
                acc[bnl][el][0] = fmaf(a, wv.x, acc[bnl][el][0]);
                acc[bnl][el][1] = fmaf(a, wv.y, acc[bnl][el][1]);
                acc[bnl][el][2] = fmaf(a, wv.z, acc[bnl][el][2]);
                acc[bnl][el][3] = fmaf(a, wv.w, acc[bnl][el][3]);
            }
        }
    }
    const float4 bov = *reinterpret_cast<const float4*>(&bo[h0]);
    #pragma unroll
    for (int bnl = 0; bnl < 2; ++bnl) {
        #pragma unroll
        for (int el = 0; el < 4; ++el) {
            float4 res = { acc[bnl][el][0] + bov.x, acc[bnl][el][1] + bov.y,
                           acc[bnl][el][2] + bov.z, acc[bnl][el][3] + bov.w };
            int e = e0 + eg * 4 + el;
            *reinterpret_cast<float4*>(&out[((bn0 + bnl) * DMD + e) * DMD + h0]) = res;
        }
    }
}

extern "C" void kernel_launch(void* const* d_in, const int* in_sizes, int n_in,
                              void* d_out, int out_size, void* d_ws, size_t ws_size,
                              hipStream_t stream) {
    const float* x       = (const float*)d_in[0];
    const float* W_emb   = (const float*)d_in[1];
    const float* b_emb   = (const float*)d_in[2];
    const float* W_start = (const float*)d_in[3];
    const float* b_start = (const float*)d_in[4];
    const float* Wel     = (const float*)d_in[5];
    const float* bel     = (const float*)d_in[6];
    const float* Wq      = (const float*)d_in[7];
    const float* bq      = (const float*)d_in[8];
    const float* Wk      = (const float*)d_in[9];
    const float* bk      = (const float*)d_in[10];
    const float* Wv      = (const float*)d_in[11];
    const float* bv      = (const float*)d_in[12];
    const float* Wo      = (const float*)d_in[13];
    const float* bo      = (const float*)d_in[14];
    const int*   f1p     = (const int*)d_in[15];
    const int*   f2p     = (const int*)d_in[16];
    float* ws  = (float*)d_ws;
    float* out = (float*)d_out;

    k_xe<<<NBN, 128, 0, stream>>>(x, W_emb, b_emb, ws);
    k_pw<<<BB, 128, 0, stream>>>(f1p, f2p, ws);
    k_vec<<<1, 128, 0, stream>>>(Wel, bel, W_start, b_start, Wq, bq, Wk, bk, Wv, bv, ws);
    k_attn<<<dim3(16, NBN), 128, 0, stream>>>(f1p, f2p, ws);
    k_out<<<256, 256, 0, stream>>>(Wo, bo, ws, out);
}

// Round 3
// 125.969 us; speedup vs baseline: 1.4426x; 1.4426x over previous
//
#include <hip/hip_runtime.h>

#define DMD 128
#define NV 64
#define BB 2
#define SQ 512
#define NBN 128                 // BB*NV
#define ASCALE 0.08838834764831845f   // 128^-0.5

// workspace layout (float offsets)
#define WS_XE  0                       // [NBN][DMD]
#define WS_PW  (WS_XE + NBN*DMD)       // [BB][2]
#define WS_VEC (WS_PW + 4)             // 9*128: Aq,Cq,Pq,Ak,Ck,Pk,Av,Cv,Pv
#define WS_OB  (WS_VEC + 9*DMD)        // [NBN][DMD][DMD] blended o

// ---------------- xe[bn][t] = sum_s x[b,s,n]*W_emb[s,t] + b_emb[t] ----------------
__global__ __launch_bounds__(128) void k_xe(const float* __restrict__ x,
                                            const float* __restrict__ W_emb,
                                            const float* __restrict__ b_emb,
                                            float* __restrict__ ws) {
    int bn = blockIdx.x;
    int b = bn >> 6, n = bn & 63;
    int t = threadIdx.x;
    __shared__ float xs[SQ];
    for (int s = t; s < SQ; s += 128) xs[s] = x[(b * SQ + s) * NV + n];
    __syncthreads();
    float acc = b_emb[t];
    for (int s = 0; s < SQ; ++s) acc = fmaf(xs[s], W_emb[s * DMD + t], acc);
    ws[WS_XE + bn * DMD + t] = acc;
}

// ---------------- period weights: table-based DFT at f1,f2 -> softmax ----------------
__global__ __launch_bounds__(128) void k_pw(const int* __restrict__ f1p,
                                            const int* __restrict__ f2p,
                                            float* __restrict__ ws) {
    int b = blockIdx.x;        // 2 blocks
    int tid = threadIdx.x;     // 128 = 64 n x 2 freqs
    __shared__ float ct[DMD], st[DMD];
    __shared__ float a2[2];
    float ang = (float)tid * 0.04908738521234052f;   // 2*pi/128
    ct[tid] = cosf(ang);
    st[tid] = sinf(ang);
    __syncthreads();
    int k = tid >> 6;          // freq slot (one wave each)
    int n = tid & 63;
    int f = k ? f2p[0] : f1p[0];
    const float* xr = ws + WS_XE + (b * NV + n) * DMD;
    float re = 0.f, im = 0.f;
    for (int t = 0; t < DMD; ++t) {
        int ph = (f * t) & (DMD - 1);
        float v = xr[t];
        re = fmaf(v, ct[ph], re);
        im = fmaf(v, st[ph], im);
    }
    float amp = sqrtf(re * re + im * im);
    for (int off = 32; off > 0; off >>= 1) amp += __shfl_down(amp, off);
    if (n == 0) a2[k] = amp * (1.0f / NV);
    __syncthreads();
    if (tid == 0) {
        float m = fmaxf(a2[0], a2[1]);
        float e0 = expf(a2[0] - m), e1 = expf(a2[1] - m);
        float inv = 1.0f / (e0 + e1);
        ws[WS_PW + b * 2 + 0] = e0 * inv;
        ws[WS_PW + b * 2 + 1] = e1 * inv;
    }
}

// ---------------- projected rank-1 vectors ----------------
__global__ __launch_bounds__(128) void k_vec(const float* __restrict__ Wel, const float* __restrict__ bel,
                                             const float* __restrict__ W_start, const float* __restrict__ b_start,
                                             const float* __restrict__ Wq, const float* __restrict__ bq,
                                             const float* __restrict__ Wk, const float* __restrict__ bk,
                                             const float* __restrict__ Wv, const float* __restrict__ bv,
                                             float* __restrict__ ws) {
    int e = threadIdx.x;
    __shared__ float A[DMD], C[DMD], BL[DMD];
    float a = 0.f, c = 0.f;
    for (int d = 0; d < DMD; ++d) {
        float w = Wel[e * DMD + d];
        a = fmaf(w, W_start[d], a);
        c = fmaf(w, b_start[d], c);
    }
    A[e] = a;
    C[e] = c + bel[e];
    BL[e] = bel[e];
    __syncthreads();
    float aq = 0, cq = 0, pq = 0, ak = 0, ck = 0, pk = 0, av = 0, cv = 0, pv = 0;
    for (int d = 0; d < DMD; ++d) {
        float Ad = A[d], Cd = C[d], Bd = BL[d];
        float wq = Wq[e * DMD + d], wk = Wk[e * DMD + d], wv = Wv[e * DMD + d];
        aq = fmaf(wq, Ad, aq); cq = fmaf(wq, Cd, cq); pq = fmaf(wq, Bd, pq);
        ak = fmaf(wk, Ad, ak); ck = fmaf(wk, Cd, ck); pk = fmaf(wk, Bd, pk);
        av = fmaf(wv, Ad, av); cv = fmaf(wv, Cd, cv); pv = fmaf(wv, Bd, pv);
    }
    float* V = ws + WS_VEC;
    V[0 * DMD + e] = aq; V[1 * DMD + e] = cq + bq[e]; V[2 * DMD + e] = pq + bq[e];
    V[3 * DMD + e] = ak; V[4 * DMD + e] = ck + bk[e]; V[5 * DMD + e] = pk + bk[e];
    V[6 * DMD + e] = av; V[7 * DMD + e] = cv + bv[e]; V[8 * DMD + e] = pv + bv[e];
}

// ============ attention paths (all inner loops compile-time bounded) ============

// Path A: P in (16,64], thread-pair per row: i = tid>>1, half = tid&1.
// g (e-independent Gram row) and w (scores) live in registers.
template<int PMAX, int NP>
__device__ __forceinline__ void attn_pathA(
    int P, int pn, int r, int Prows, int e0, int br, float pwv,
    const float* __restrict__ V, const float* xs, const float* U,
    const float* xt, float (*obuf)[132], int tid)
{
    const int UH = PMAX / 2;
    int i = tid >> 1, half = tid & 1;
    bool rowact = (i < Prows);
    int ic = rowact ? i : (Prows - 1);
    bool rowvalid = (ic < r);

    float g[UH];
#pragma unroll
    for (int u = 0; u < UH; ++u) g[u] = 0.f;
    for (int p = 0; p < pn - 1; ++p) {
        float xi = xs[p * P + ic];
#pragma unroll
        for (int u = 0; u < UH; ++u) {
            int j = half * UH + u;
            int jc = (j < P) ? j : 0;
            float t = fmaf(xi, xs[p * P + jc], g[u]);
            g[u] = (j < P) ? t : 0.f;
        }
    }

    for (int ec = 0; ec < 8; ++ec) {
        int e = e0 + ec;
        float Aq = V[0*DMD+e], Cq = V[1*DMD+e], Pq = V[2*DMD+e];
        float Ak = V[3*DMD+e], Ck = V[4*DMD+e], Pk = V[5*DMD+e];
        float Av = V[6*DMD+e], Cv = V[7*DMD+e], Pv = V[8*DMD+e];
        float c1 = ASCALE*Aq*Ak, c2 = ASCALE*Aq*Ck, c3 = ASCALE*Cq*Ak;
        float c4 = ASCALE*(float)(pn-1)*Cq*Ck;
        float h = fmaf(c2, U[ic], c4);
        float asi = ASCALE * (rowvalid ? fmaf(xt[ic], Aq, Cq) : Pq);

        float w[UH];
        float m = -1e30f;
#pragma unroll
        for (int u = 0; u < UH; ++u) {
            int j = half * UH + u;
            int jc = (j < P) ? j : 0;
            float bK = (j < r) ? fmaf(xt[jc], Ak, Ck) : Pk;
            float S = fmaf(c1, g[u], fmaf(c3, U[jc], fmaf(asi, bK, h)));
            S = (j < P) ? S : -1e30f;
            w[u] = S;
            m = fmaxf(m, S);
        }
        m = fmaxf(m, __shfl_xor(m, 1));
        float l = 0.f, wr = 0.f;
#pragma unroll
        for (int u = 0; u < UH; ++u) {
            int j = half * UH + u;
            float ev = __expf(w[u] - m);
            ev = (j < P) ? ev : 0.f;
            w[u] = ev;
            l += ev;
            wr += (j < r) ? ev : 0.f;
        }
        l += __shfl_xor(l, 1);
        wr += __shfl_xor(wr, 1);
        float li = 1.f / l;

        float accq[NP];
#pragma unroll
        for (int q = 0; q < NP; ++q) accq[q] = 0.f;
#pragma unroll
        for (int q = 0; q < NP; ++q) {
            if (q < pn) {
                bool lastq = (q == pn - 1);
                float a = 0.f;
#pragma unroll
                for (int u = 0; u < UH; ++u) {
                    int j = half * UH + u;
                    int idx = q * P + j;
                    idx = (idx < DMD) ? idx : 0;
                    float wm = (lastq && j >= r) ? 0.f : w[u];
                    a = fmaf(wm, xs[idx], a);
                }
                accq[q] = a;
            }
        }
#pragma unroll
        for (int q = 0; q < NP; ++q) {
            float a = accq[q] + __shfl_xor(accq[q], 1);
            if (q < pn && half == 0 && rowact) {
                int mo = i * pn + q;
                if (mo < DMD) {
                    float o;
                    if (q == pn - 1) {
                        float sl = wr * li;
                        o = fmaf(Av, a * li, fmaf(Cv, sl, Pv * (1.f - sl)));
                    } else {
                        o = fmaf(Av, a * li, Cv);
                    }
                    float val = pwv * o;
                    if (br == 0) obuf[ec][mo] = val;
                    else         obuf[ec][mo] += val;
                }
            }
        }
    }
}

// Path B: P <= 16 (pn >= 8). Thread per output mo; Gram matrix G in LDS (<=256).
__device__ __forceinline__ void attn_pathB(
    int P, int pn, int r, int Prows, int e0, int br, float pwv,
    const float* __restrict__ V, const float* xs, const float* U,
    const float* xt, const float* G, float (*obuf)[132], int tid)
{
    const int UB = 16;
    int i2 = tid / pn;
    int p2 = tid - i2 * pn;
    bool lastp = (p2 == pn - 1);
    bool rowvalid = (i2 < r);
    int base = p2 * P;

    for (int ec = 0; ec < 8; ++ec) {
        int e = e0 + ec;
        float Aq = V[0*DMD+e], Cq = V[1*DMD+e], Pq = V[2*DMD+e];
        float Ak = V[3*DMD+e], Ck = V[4*DMD+e], Pk = V[5*DMD+e];
        float Av = V[6*DMD+e], Cv = V[7*DMD+e], Pv = V[8*DMD+e];
        float c1 = ASCALE*Aq*Ak, c2 = ASCALE*Aq*Ck, c3 = ASCALE*Cq*Ak;
        float c4 = ASCALE*(float)(pn-1)*Cq*Ck;
        float h = fmaf(c2, U[i2], c4);
        float asi = ASCALE * (rowvalid ? fmaf(xt[i2], Aq, Cq) : Pq);

        float w[UB];
        float m = -1e30f;
#pragma unroll
        for (int j = 0; j < UB; ++j) {
            int jc = (j < P) ? j : 0;
            float bK = (j < r) ? fmaf(xt[jc], Ak, Ck) : Pk;
            float S = fmaf(c1, G[i2 * P + jc], fmaf(c3, U[jc], fmaf(asi, bK, h)));
            S = (j < P) ? S : -1e30f;
            w[j] = S;
            m = fmaxf(m, S);
        }
        float l = 0.f, wr = 0.f, accx = 0.f;
#pragma unroll
        for (int j = 0; j < UB; ++j) {
            float ev = __expf(w[j] - m);
            ev = (j < P) ? ev : 0.f;
            l += ev;
            wr += (j < r) ? ev : 0.f;
            float wm = (lastp && j >= r) ? 0.f : ev;
            int idx = base + j;
            idx = (idx < DMD) ? idx : 0;
            accx = fmaf(wm, xs[idx], accx);
        }
        float li = 1.f / l;
        float o;
        if (lastp) { float sl = wr * li; o = fmaf(Av, accx * li, fmaf(Cv, sl, Pv * (1.f - sl))); }
        else       o = fmaf(Av, accx * li, Cv);
        float val = pwv * o;
        if (br == 0) obuf[ec][tid] = val;
        else         obuf[ec][tid] += val;
    }
}

// Rank-1: P == 128 (f == 1, pn == 1) — S[i,j] = aS_i * bK_j
__device__ __forceinline__ void attn_rank1(
    int e0, int br, float pwv, const float* __restrict__ V,
    const float* xs, float (*obuf)[132], int tid)
{
    float xi = xs[tid];
    for (int ec = 0; ec < 8; ++ec) {
        int e = e0 + ec;
        float Aq = V[0*DMD+e], Cq = V[1*DMD+e];
        float Ak = V[3*DMD+e], Ck = V[4*DMD+e];
        float Av = V[6*DMD+e], Cv = V[7*DMD+e];
        float asi = ASCALE * fmaf(xi, Aq, Cq);
        float m = -1e30f;
#pragma unroll 16
        for (int j = 0; j < DMD; ++j) {
            float bK = fmaf(xs[j], Ak, Ck);
            m = fmaxf(m, asi * bK);
        }
        float l = 0.f, accx = 0.f;
#pragma unroll 16
        for (int j = 0; j < DMD; ++j) {
            float bK = fmaf(xs[j], Ak, Ck);
            float ev = __expf(fmaf(asi, bK, -m));
            l += ev;
            accx = fmaf(ev, xs[j], accx);
        }
        float o = fmaf(Av, accx / l, Cv);
        float val = pwv * o;
        if (br == 0) obuf[ec][tid] = val;
        else         obuf[ec][tid] += val;
    }
}

__global__ __launch_bounds__(128) void k_attn(const int* __restrict__ f1p,
                                              const int* __restrict__ f2p,
                                              float* __restrict__ ws) {
    int bn = blockIdx.y;
    int b = bn >> 6;
    int e0 = blockIdx.x * 8;
    int tid = threadIdx.x;

    __shared__ float xs[DMD];
    __shared__ float U[64], xt[64];
    __shared__ float G[256];
    __shared__ float obuf[8][132];

    xs[tid] = ws[WS_XE + bn * DMD + tid];
    const float* V = ws + WS_VEC;
    int fv0 = f1p[0], fv1 = f2p[0];
    float pw0 = ws[WS_PW + b * 2 + 0];
    float pw1 = ws[WS_PW + b * 2 + 1];
    __syncthreads();

    for (int br = 0; br < 2; ++br) {
        int f = br ? fv1 : fv0;
        float pwv = br ? pw1 : pw0;
        int P = DMD / f;
        int pn = (DMD + P - 1) / P;
        int r = DMD - (pn - 1) * P;
        int Prows = (DMD + pn - 1) / pn;

        if (br == 1) __syncthreads();      // br0 obuf writes visible before br1 RMW

        if (P == DMD) {
            attn_rank1(e0, br, pwv, V, xs, obuf, tid);
        } else {
            if (br == 0) __syncthreads();  // (uniform; pairs with br==1 barrier above)
            if (tid < 64) {
                int j = tid;
                if (j < P) {
                    float s = 0.f;
                    for (int p = 0; p < pn - 1; ++p) s += xs[p * P + j];
                    U[j] = s;
                    xt[j] = (j < r) ? xs[(pn - 1) * P + j] : 0.f;
                }
            }
            if (P <= 16) {
                int tot = Prows * P;       // <= 256
                for (int idx = tid; idx < tot; idx += 128) {
                    int gi = idx / P, gj = idx - gi * P;
                    float s = 0.f;
                    for (int p = 0; p < pn - 1; ++p)
                        s = fmaf(xs[p * P + gi], xs[p * P + gj], s);
                    G[idx] = s;
                }
            }
            __syncthreads();

            if (P > 32) {
                if (pn == 2) attn_pathA<64, 2>(P, pn, r, Prows, e0, br, pwv, V, xs, U, xt, obuf, tid);
                else         attn_pathA<64, 4>(P, pn, r, Prows, e0, br, pwv, V, xs, U, xt, obuf, tid);
            } else if (P > 16) {
                attn_pathA<32, 8>(P, pn, r, Prows, e0, br, pwv, V, xs, U, xt, obuf, tid);
            } else {
                attn_pathB(P, pn, r, Prows, e0, br, pwv, V, xs, U, xt, G, obuf, tid);
            }
        }
    }
    __syncthreads();
    for (int ec = 0; ec < 8; ++ec)
        ws[WS_OB + (bn * DMD + e0 + ec) * DMD + tid] = obuf[ec][tid];
}

// ---------------- out[bn][e][h] = sum_m oblend[bn][e][m]*Wo[h][m] + bo[h] ----------------
__global__ __launch_bounds__(256) void k_out(const float* __restrict__ Wo,
                                             const float* __restrict__ bo,
                                             const float* __restrict__ ws,
                                             float* __restrict__ out) {
    int blk = blockIdx.x;          // 256 = 64 bn-pairs * 4 e-quarters
    int bn0 = (blk >> 2) * 2;
    int e0  = (blk & 3) * 32;
    int tid = threadIdx.x;
    __shared__ __align__(16) float WT[DMD * 132];   // WT[m*132+h] = Wo[h][m]
    __shared__ float orow[2][32][DMD];
    for (int idx = tid; idx < DMD * DMD; idx += 256) {
        int h = idx >> 7, m = idx & 127;
        WT[m * 132 + h] = Wo[idx];
    }
    for (int idx = tid; idx < 2 * 32 * DMD; idx += 256) {
        int bnl = idx >> 12;
        int rem = idx & 4095;
        int e = rem >> 7, m = rem & 127;
        orow[bnl][e][m] = ws[WS_OB + ((bn0 + bnl) * DMD + e0 + e) * DMD + m];
    }
    __syncthreads();
    int hg = tid & 31;
    int eg = tid >> 5;             // 0..7
    int h0 = hg * 4;
    float acc[2][4][4];
    #pragma unroll
    for (int a = 0; a < 2; ++a)
        #pragma unroll
        for (int c = 0; c < 4; ++c)
            #pragma unroll
            for (int d = 0; d < 4; ++d) acc[a][c][d] = 0.f;

    #pragma unroll 2
    for (int m = 0; m < DMD; ++m) {
        const float4 wv = *reinterpret_cast<const float4*>(&WT[m * 132 + h0]);
        #pragma unroll
        for (int bnl = 0; bnl < 2; ++bnl) {
            #pragma unroll
            for (int el = 0; el < 4; ++el) {
                float a = orow[bnl][eg * 4 + el][m];
                acc[bnl][el][0] = fmaf(a, wv.x, acc[bnl][el][0]);
                acc[bnl][el][1] = fmaf(a, wv.y, acc[bnl][el][1]);
                acc[bnl][el][2] = fmaf(a, wv.z, acc[bnl][el][2]);
                acc[bnl][el][3] = fmaf(a, wv.w, acc[bnl][el][3]);
            }
        }
    }
    const float4 bov = *reinterpret_cast<const float4*>(&bo[h0]);
    #pragma unroll
    for (int bnl = 0; bnl < 2; ++bnl) {
        #pragma unroll
        for (int el = 0; el < 4; ++el) {
            float4 res = { acc[bnl][el][0] + bov.x, acc[bnl][el][1] + bov.y,
                           acc[bnl][el][2] + bov.z, acc[bnl][el][3] + bov.w };
            int e = e0 + eg * 4 + el;
            *reinterpret_cast<float4*>(&out[((bn0 + bnl) * DMD + e) * DMD + h0]) = res;
        }
    }
}

extern "C" void kernel_launch(void* const* d_in, const int* in_sizes, int n_in,
                              void* d_out, int out_size, void* d_ws, size_t ws_size,
                              hipStream_t stream) {
    const float* x       = (const float*)d_in[0];
    const float* W_emb   = (const float*)d_in[1];
    const float* b_emb   = (const float*)d_in[2];
    const float* W_start = (const float*)d_in[3];
    const float* b_start = (const float*)d_in[4];
    const float* Wel     = (const float*)d_in[5];
    const float* bel     = (const float*)d_in[6];
    const float* Wq      = (const float*)d_in[7];
    const float* bq      = (const float*)d_in[8];
    const float* Wk      = (const float*)d_in[9];
    const float* bk      = (const float*)d_in[10];
    const float* Wv      = (const float*)d_in[11];
    const float* bv      = (const float*)d_in[12];
    const float* Wo      = (const float*)d_in[13];
    const float* bo      = (const float*)d_in[14];
    const int*   f1p     = (const int*)d_in[15];
    const int*   f2p     = (const int*)d_in[16];
    float* ws  = (float*)d_ws;
    float* out = (float*)d_out;

    k_xe<<<NBN, 128, 0, stream>>>(x, W_emb, b_emb, ws);
    k_pw<<<BB, 128, 0, stream>>>(f1p, f2p, ws);
    k_vec<<<1, 128, 0, stream>>>(Wel, bel, W_start, b_start, Wq, bq, Wk, bk, Wv, bv, ws);
    k_attn<<<dim3(16, NBN), 128, 0, stream>>>(f1p, f2p, ws);
    k_out<<<256, 256, 0, stream>>>(Wo, bo, ws, out);
}

// Round 4
// 91.553 us; speedup vs baseline: 1.9849x; 1.3759x over previous
//
#include <hip/hip_runtime.h>

#define DMD 128
#define NV 64
#define BB 2
#define SQ 512
#define NBN 128                 // BB*NV
#define ASCALE 0.08838834764831845f   // 128^-0.5
#define L2E 1.4426950408889634f
#define CSC (ASCALE * L2E)

// workspace layout (float offsets)
#define WS_XE  0                       // [NBN][DMD]
#define WS_PW  (WS_XE + NBN*DMD)       // [BB][2]
#define WS_VEC (WS_PW + 4)             // 9*128
#define WS_OB  (WS_VEC + 9*DMD)        // [NBN][DMD][DMD]

// ---------------- xe[bn][t] = sum_s x[b,s,n]*W_emb[s,t] + b_emb[t] ----------------
__global__ __launch_bounds__(512) void k_xe(const float* __restrict__ x,
                                            const float* __restrict__ W_emb,
                                            const float* __restrict__ b_emb,
                                            float* __restrict__ ws) {
    int bn = blockIdx.x;
    int b = bn >> 6, n = bn & 63;
    int tid = threadIdx.x;
    int t = tid & 127, sc = tid >> 7;
    __shared__ float xsh[SQ];
    __shared__ float part[3][DMD];
    xsh[tid] = x[(b * SQ + tid) * NV + n];
    __syncthreads();
    float acc = 0.f;
    const float* W = W_emb + (sc * 128) * DMD + t;
#pragma unroll 8
    for (int s = 0; s < 128; ++s) acc = fmaf(xsh[sc * 128 + s], W[s * DMD], acc);
    if (sc) part[sc - 1][t] = acc;
    __syncthreads();
    if (sc == 0)
        ws[WS_XE + bn * DMD + t] = acc + part[0][t] + part[1][t] + part[2][t] + b_emb[t];
}

// ---------------- merged: period weights (blocks 0,1) + rank-1 vectors (block 2) ----------------
__global__ __launch_bounds__(128) void k_prep(const int* __restrict__ f1p,
                                              const int* __restrict__ f2p,
                                              const float* __restrict__ Wel, const float* __restrict__ bel,
                                              const float* __restrict__ W_start, const float* __restrict__ b_start,
                                              const float* __restrict__ Wq, const float* __restrict__ bq,
                                              const float* __restrict__ Wk, const float* __restrict__ bk,
                                              const float* __restrict__ Wv, const float* __restrict__ bv,
                                              float* __restrict__ ws) {
    int tid = threadIdx.x;
    __shared__ float ct[DMD], st[DMD];
    __shared__ float a2[2];
    __shared__ float A[DMD], C[DMD], BL[DMD];
    if (blockIdx.x < 2) {
        int b = blockIdx.x;
        float ang = (float)tid * 0.04908738521234052f;   // 2*pi/128
        ct[tid] = cosf(ang);
        st[tid] = sinf(ang);
        __syncthreads();
        int k = tid >> 6;
        int n = tid & 63;
        int f = k ? f2p[0] : f1p[0];
        const float* xr = ws + WS_XE + (b * NV + n) * DMD;
        float re = 0.f, im = 0.f;
        for (int t = 0; t < DMD; ++t) {
            int ph = (f * t) & (DMD - 1);
            float v = xr[t];
            re = fmaf(v, ct[ph], re);
            im = fmaf(v, st[ph], im);
        }
        float amp = sqrtf(re * re + im * im);
        for (int off = 32; off > 0; off >>= 1) amp += __shfl_down(amp, off);
        if (n == 0) a2[k] = amp * (1.0f / NV);
        __syncthreads();
        if (tid == 0) {
            float m = fmaxf(a2[0], a2[1]);
            float e0 = expf(a2[0] - m), e1 = expf(a2[1] - m);
            float inv = 1.0f / (e0 + e1);
            ws[WS_PW + b * 2 + 0] = e0 * inv;
            ws[WS_PW + b * 2 + 1] = e1 * inv;
        }
    } else {
        int e = tid;
        float a = 0.f, c = 0.f;
        for (int d = 0; d < DMD; ++d) {
            float w = Wel[e * DMD + d];
            a = fmaf(w, W_start[d], a);
            c = fmaf(w, b_start[d], c);
        }
        A[e] = a;
        C[e] = c + bel[e];
        BL[e] = bel[e];
        __syncthreads();
        float aq = 0, cq = 0, pq = 0, ak = 0, ck = 0, pk = 0, av = 0, cv = 0, pv = 0;
        for (int d = 0; d < DMD; ++d) {
            float Ad = A[d], Cd = C[d], Bd = BL[d];
            float wq = Wq[e * DMD + d], wk = Wk[e * DMD + d], wv = Wv[e * DMD + d];
            aq = fmaf(wq, Ad, aq); cq = fmaf(wq, Cd, cq); pq = fmaf(wq, Bd, pq);
            ak = fmaf(wk, Ad, ak); ck = fmaf(wk, Cd, ck); pk = fmaf(wk, Bd, pk);
            av = fmaf(wv, Ad, av); cv = fmaf(wv, Cd, cv); pv = fmaf(wv, Bd, pv);
        }
        float* V = ws + WS_VEC;
        V[0 * DMD + e] = aq; V[1 * DMD + e] = cq + bq[e]; V[2 * DMD + e] = pq + bq[e];
        V[3 * DMD + e] = ak; V[4 * DMD + e] = ck + bk[e]; V[5 * DMD + e] = pk + bk[e];
        V[6 * DMD + e] = av; V[7 * DMD + e] = cv + bv[e]; V[8 * DMD + e] = pv + bv[e];
    }
}

// ============ attention paths: register-resident inner loops ============

// Path A: P in 17..64. 4 lanes per row; per-lane j-slice of UH columns in registers.
template<int UH, int NP>
__device__ __forceinline__ void attn_pathA(
    int P, int pn, int r, int Prows, int e0, int br, float pwv,
    const float* __restrict__ V, const float* xs, const float* U,
    const float* xt, float (*obuf)[132], int tid)
{
    int lane4 = tid & 3;
    int i0 = tid >> 2;
    int jb = lane4 * UH;

    // row-independent register loads (reused across rows/e's)
    float Ur[UH], xtr[UH], xq0[UH], xq1[UH];
#pragma unroll
    for (int u = 0; u < UH; ++u) {
        int j = jb + u, jc = (j < P) ? j : 0;
        Ur[u] = U[jc];
        xtr[u] = xt[jc];
        xq0[u] = (j < DMD) ? xs[j] : 0.f;           // q = 0 (j < P <= 64 anyway)
        int i1 = P + j;
        xq1[u] = (i1 < DMD) ? xs[i1] : 0.f;         // q = 1
    }

    int nrep = (Prows > 32) ? 2 : 1;
    for (int rep = 0; rep < nrep; ++rep) {
        int i = i0 + rep * 32;
        bool rowact = (i < Prows);
        int ic = rowact ? i : 0;
        float xtic = xt[ic];
        bool rowvalid = (ic < r);

        float g[UH];
#pragma unroll
        for (int u = 0; u < UH; ++u) g[u] = 0.f;
        for (int p = 0; p < pn - 1; ++p) {
            float xi = xs[p * P + ic];
#pragma unroll
            for (int u = 0; u < UH; ++u) {
                int j = jb + u, jc = (j < P) ? j : 0;
                g[u] = fmaf(xi, xs[p * P + jc], g[u]);
            }
        }

        for (int ec = 0; ec < 8; ++ec) {
            int e = e0 + ec;
            float Aq = V[e],        Cq = V[DMD + e],   Pq = V[2 * DMD + e];
            float Ak = V[3 * DMD + e], Ck = V[4 * DMD + e], Pk = V[5 * DMD + e];
            float Av = V[6 * DMD + e], Cv = V[7 * DMD + e], Pv = V[8 * DMD + e];
            float c1 = CSC * Aq * Ak, c3 = CSC * Cq * Ak;
            float asi = CSC * (rowvalid ? fmaf(xtic, Aq, Cq) : Pq);

            float l0 = 0.f, l1 = 0.f, w0 = 0.f, w1 = 0.f;
            float accq[NP];
#pragma unroll
            for (int q = 0; q < NP; ++q) accq[q] = 0.f;

#pragma unroll
            for (int u = 0; u < UH; ++u) {
                int j = jb + u;
                float bK = (j < r) ? fmaf(xtr[u], Ak, Ck) : Pk;
                float S = fmaf(asi, bK, fmaf(c3, Ur[u], c1 * g[u]));
                float ev = exp2f(S);
                ev = (j < P) ? ev : 0.f;
                if (u & 1) l1 += ev; else l0 += ev;
                float evr = (j < r) ? ev : 0.f;
                if (u & 1) w1 += evr; else w0 += evr;
                accq[0] = fmaf(ev, xq0[u], accq[0]);
                if (NP >= 2) accq[1] = fmaf(ev, xq1[u], accq[1]);
#pragma unroll
                for (int q = 2; q < NP; ++q) {
                    int idx = q * P + j;          // >= 128 automatically for q >= pn or padded tail
                    float xv = (idx < DMD) ? xs[idx] : 0.f;
                    accq[q] = fmaf(ev, xv, accq[q]);
                }
            }
            float l = l0 + l1, wr = w0 + w1;
            l += __shfl_xor(l, 1);  l += __shfl_xor(l, 2);
            wr += __shfl_xor(wr, 1); wr += __shfl_xor(wr, 2);
#pragma unroll
            for (int q = 0; q < NP; ++q) {
                if (q < pn) {
                    accq[q] += __shfl_xor(accq[q], 1);
                    accq[q] += __shfl_xor(accq[q], 2);
                }
            }
            if (lane4 == 0 && rowact) {
                float li = 1.f / l;
#pragma unroll
                for (int q = 0; q < NP; ++q) {
                    if (q < pn) {
                        int mo = i * pn + q;
                        if (mo < DMD) {
                            float o;
                            if (q == pn - 1) {
                                float sl = wr * li;
                                o = fmaf(Av, accq[q] * li, fmaf(Cv, sl, Pv * (1.f - sl)));
                            } else {
                                o = fmaf(Av, accq[q] * li, Cv);
                            }
                            float val = pwv * o;
                            if (br == 0) obuf[ec][mo] = val;
                            else         obuf[ec][mo] += val;
                        }
                    }
                }
            }
        }
    }
}

// Path B: P <= 16. Thread per output; full row in registers.
__device__ __forceinline__ void attn_pathB(
    int P, int pn, int r, int Prows, int e0, int br, float pwv,
    const float* __restrict__ V, const float* xs, const float* U,
    const float* xt, const float* G, float (*obuf)[132], int tid)
{
    int i2 = tid / pn, p2 = tid - i2 * pn;
    bool lastp = (p2 == pn - 1);
    bool rowvalid = (i2 < r);
    float xti = xt[i2];

    float Gr[16], xsr[16], Urr[16], xtr[16];
#pragma unroll
    for (int j = 0; j < 16; ++j) {
        int jc = (j < P) ? j : 0;
        Gr[j] = G[i2 * P + jc];
        Urr[j] = U[jc];
        xtr[j] = xt[jc];
        int idx = p2 * P + j;
        xsr[j] = (idx < DMD && j < P) ? xs[idx] : 0.f;   // auto-zeros padded tail
    }

    for (int ec = 0; ec < 8; ++ec) {
        int e = e0 + ec;
        float Aq = V[e],        Cq = V[DMD + e],   Pq = V[2 * DMD + e];
        float Ak = V[3 * DMD + e], Ck = V[4 * DMD + e], Pk = V[5 * DMD + e];
        float Av = V[6 * DMD + e], Cv = V[7 * DMD + e], Pv = V[8 * DMD + e];
        float c1 = CSC * Aq * Ak, c3 = CSC * Cq * Ak;
        float asi = CSC * (rowvalid ? fmaf(xti, Aq, Cq) : Pq);

        float l0 = 0.f, l1 = 0.f, w0 = 0.f, w1 = 0.f, a0 = 0.f, a1 = 0.f;
#pragma unroll
        for (int j = 0; j < 16; ++j) {
            float bK = (j < r) ? fmaf(xtr[j], Ak, Ck) : Pk;
            float S = fmaf(asi, bK, fmaf(c3, Urr[j], c1 * Gr[j]));
            float ev = exp2f(S);
            ev = (j < P) ? ev : 0.f;
            if (j & 1) l1 += ev; else l0 += ev;
            float evr = (j < r) ? ev : 0.f;
            if (j & 1) w1 += evr; else w0 += evr;
            if (j & 1) a1 = fmaf(ev, xsr[j], a1); else a0 = fmaf(ev, xsr[j], a0);
        }
        float l = l0 + l1, wr = w0 + w1, accx = a0 + a1;
        float li = 1.f / l;
        float o;
        if (lastp) { float sl = wr * li; o = fmaf(Av, accx * li, fmaf(Cv, sl, Pv * (1.f - sl))); }
        else       o = fmaf(Av, accx * li, Cv);
        float val = pwv * o;
        if (br == 0) obuf[ec][tid] = val;
        else         obuf[ec][tid] += val;
    }
}

// Rank-1: P == 128 (f == 1): w_j ∝ exp(t_i * xs_j); e-batched j-loop.
__device__ __forceinline__ void attn_rank1(
    int e0, int br, float pwv, const float* __restrict__ V,
    const float* xs, float (*obuf)[132], int tid)
{
    float xi = xs[tid];
    float t[8], l[8], ax[8];
#pragma unroll
    for (int k = 0; k < 8; ++k) {
        int e = e0 + k;
        float Aq = V[e], Cq = V[DMD + e], Ak = V[3 * DMD + e];
        t[k] = CSC * fmaf(xi, Aq, Cq) * Ak;
        l[k] = 0.f; ax[k] = 0.f;
    }
#pragma unroll 4
    for (int j = 0; j < DMD; ++j) {
        float xj = xs[j];
#pragma unroll
        for (int k = 0; k < 8; ++k) {
            float ev = exp2f(t[k] * xj);
            l[k] += ev;
            ax[k] = fmaf(ev, xj, ax[k]);
        }
    }
#pragma unroll
    for (int k = 0; k < 8; ++k) {
        int e = e0 + k;
        float Av = V[6 * DMD + e], Cv = V[7 * DMD + e];
        float o = fmaf(Av, ax[k] / l[k], Cv);
        float val = pwv * o;
        if (br == 0) obuf[k][tid] = val;
        else         obuf[k][tid] += val;
    }
}

__global__ __launch_bounds__(128) void k_attn(const int* __restrict__ f1p,
                                              const int* __restrict__ f2p,
                                              float* __restrict__ ws) {
    int bn = blockIdx.y;
    int b = bn >> 6;
    int e0 = blockIdx.x * 8;
    int tid = threadIdx.x;

    __shared__ float xs[DMD], U[64], xt[64], G[256];
    __shared__ float obuf[8][132];

    xs[tid] = ws[WS_XE + bn * DMD + tid];
    int fv0 = f1p[0], fv1 = f2p[0];
    float pw0 = ws[WS_PW + b * 2 + 0];
    float pw1 = ws[WS_PW + b * 2 + 1];
    const float* V = ws + WS_VEC;
    __syncthreads();

    for (int br = 0; br < 2; ++br) {
        int f = br ? fv1 : fv0;
        float pwv = br ? pw1 : pw0;
        int P = DMD / f;
        int pn = (DMD + P - 1) / P;
        int r = DMD - (pn - 1) * P;
        int Prows = (DMD + pn - 1) / pn;

        if (br == 1) __syncthreads();   // obuf RAW + shared refill protection

        if (P == DMD) {
            attn_rank1(e0, br, pwv, V, xs, obuf, tid);
        } else {
            if (tid < P) {
                float s = 0.f;
                for (int p = 0; p < pn - 1; ++p) s += xs[p * P + tid];
                U[tid] = s;
                xt[tid] = (tid < r) ? xs[(pn - 1) * P + tid] : 0.f;
            }
            if (P <= 16) {
                int tot = Prows * P;       // <= 256
                for (int idx = tid; idx < tot; idx += 128) {
                    int gi = idx / P, gj = idx - gi * P;
                    float s = 0.f;
                    for (int p = 0; p < pn - 1; ++p)
                        s = fmaf(xs[p * P + gi], xs[p * P + gj], s);
                    G[idx] = s;
                }
            }
            __syncthreads();

            if (P > 32) {
                if (pn == 2) attn_pathA<16, 2>(P, pn, r, Prows, e0, br, pwv, V, xs, U, xt, obuf, tid);
                else         attn_pathA<16, 4>(P, pn, r, Prows, e0, br, pwv, V, xs, U, xt, obuf, tid);
            } else if (P > 16) {
                attn_pathA<8, 8>(P, pn, r, Prows, e0, br, pwv, V, xs, U, xt, obuf, tid);
            } else {
                attn_pathB(P, pn, r, Prows, e0, br, pwv, V, xs, U, xt, G, obuf, tid);
            }
        }
    }
    __syncthreads();
    for (int ec = 0; ec < 8; ++ec)
        ws[WS_OB + (bn * DMD + e0 + ec) * DMD + tid] = obuf[ec][tid];
}

// ---------------- out[bn][e][h] = sum_m ob[bn][e][m]*Wo[h][m] + bo[h], m-chunked ----------------
__global__ __launch_bounds__(256) void k_out(const float* __restrict__ Wo,
                                             const float* __restrict__ bo,
                                             const float* __restrict__ ws,
                                             float* __restrict__ out) {
    int blk = blockIdx.x;          // 256 = 64 bn-pairs * 4 e-quarters
    int bn0 = (blk >> 2) * 2;
    int e0  = (blk & 3) * 32;
    int tid = threadIdx.x;
    __shared__ __align__(16) float WTc[32 * 132];    // [mm][h]
    __shared__ __align__(16) float oT[2][32][36];    // [bnl][mm][e]
    int hg = tid & 31, eg = tid >> 5, h0 = hg * 4;

    float acc[2][4][4];
#pragma unroll
    for (int a = 0; a < 2; ++a)
#pragma unroll
        for (int c = 0; c < 4; ++c)
#pragma unroll
            for (int d = 0; d < 4; ++d) acc[a][c][d] = 0.f;

    for (int mc = 0; mc < 4; ++mc) {
        int m0 = mc * 32;
        __syncthreads();
        for (int idx = tid; idx < 4096; idx += 256) {
            int h = idx >> 5, mm = idx & 31;
            WTc[mm * 132 + h] = Wo[h * DMD + m0 + mm];
        }
        for (int idx = tid; idx < 2048; idx += 256) {
            int bnl = idx >> 10, rem = idx & 1023, e = rem >> 5, mm = rem & 31;
            oT[bnl][mm][e] = ws[WS_OB + ((bn0 + bnl) * DMD + e0 + e) * DMD + m0 + mm];
        }
        __syncthreads();
#pragma unroll 4
        for (int mm = 0; mm < 32; ++mm) {
            const float4 wv = *reinterpret_cast<const float4*>(&WTc[mm * 132 + h0]);
            const float4 q0 = *reinterpret_cast<const float4*>(&oT[0][mm][eg * 4]);
            const float4 q1 = *reinterpret_cast<const float4*>(&oT[1][mm][eg * 4]);
            float ae[2][4] = {{q0.x, q0.y, q0.z, q0.w}, {q1.x, q1.y, q1.z, q1.w}};
#pragma unroll
            for (int bnl = 0; bnl < 2; ++bnl) {
#pragma unroll
                for (int el = 0; el < 4; ++el) {
                    float a = ae[bnl][el];
                    acc[bnl][el][0] = fmaf(a, wv.x, acc[bnl][el][0]);
                    acc[bnl][el][1] = fmaf(a, wv.y, acc[bnl][el][1]);
                    acc[bnl][el][2] = fmaf(a, wv.z, acc[bnl][el][2]);
                    acc[bnl][el][3] = fmaf(a, wv.w, acc[bnl][el][3]);
                }
            }
        }
    }
    const float4 bov = *reinterpret_cast<const float4*>(&bo[h0]);
#pragma unroll
    for (int bnl = 0; bnl < 2; ++bnl) {
#pragma unroll
        for (int el = 0; el < 4; ++el) {
            float4 res = { acc[bnl][el][0] + bov.x, acc[bnl][el][1] + bov.y,
                           acc[bnl][el][2] + bov.z, acc[bnl][el][3] + bov.w };
            int e = e0 + eg * 4 + el;
            *reinterpret_cast<float4*>(&out[((bn0 + bnl) * DMD + e) * DMD + h0]) = res;
        }
    }
}

extern "C" void kernel_launch(void* const* d_in, const int* in_sizes, int n_in,
                              void* d_out, int out_size, void* d_ws, size_t ws_size,
                              hipStream_t stream) {
    const float* x       = (const float*)d_in[0];
    const float* W_emb   = (const float*)d_in[1];
    const float* b_emb   = (const float*)d_in[2];
    const float* W_start = (const float*)d_in[3];
    const float* b_start = (const float*)d_in[4];
    const float* Wel     = (const float*)d_in[5];
    const float* bel     = (const float*)d_in[6];
    const float* Wq      = (const float*)d_in[7];
    const float* bq      = (const float*)d_in[8];
    const float* Wk      = (const float*)d_in[9];
    const float* bk      = (const float*)d_in[10];
    const float* Wv      = (const float*)d_in[11];
    const float* bv      = (const float*)d_in[12];
    const float* Wo      = (const float*)d_in[13];
    const float* bo      = (const float*)d_in[14];
    const int*   f1p     = (const int*)d_in[15];
    const int*   f2p     = (const int*)d_in[16];
    float* ws  = (float*)d_ws;
    float* out = (float*)d_out;

    k_xe<<<NBN, 512, 0, stream>>>(x, W_emb, b_emb, ws);
    k_prep<<<3, 128, 0, stream>>>(f1p, f2p, Wel, bel, W_start, b_start,
                                  Wq, bq, Wk, bk, Wv, bv, ws);
    k_attn<<<dim3(16, NBN), 128, 0, stream>>>(f1p, f2p, ws);
    k_out<<<256, 256, 0, stream>>>(Wo, bo, ws, out);
}

// Round 5
// 81.952 us; speedup vs baseline: 2.2175x; 1.1172x over previous
//
#include <hip/hip_runtime.h>

#define DMD 128
#define NV 64
#define BB 2
#define SQ 512
#define NBN 128                 // BB*NV
#define ASCALE 0.08838834764831845f   // 128^-0.5
#define L2E 1.4426950408889634f
#define CSC (ASCALE * L2E)

// workspace layout (float offsets)
#define WS_XE  0                       // [NBN][DMD]
#define WS_PW  (WS_XE + NBN*DMD)       // [BB][2]
#define WS_VEC (WS_PW + 4)             // 9*128
#define WS_OB  (WS_VEC + 9*DMD)        // [NBN][DMD][DMD]

// ---------------- xe[bn][t] = sum_s x[b,s,n]*W_emb[s,t] + b_emb[t] ----------------
__global__ __launch_bounds__(512) void k_xe(const float* __restrict__ x,
                                            const float* __restrict__ W_emb,
                                            const float* __restrict__ b_emb,
                                            float* __restrict__ ws) {
    int bn = blockIdx.x;
    int b = bn >> 6, n = bn & 63;
    int tid = threadIdx.x;
    int t = tid & 127, sc = tid >> 7;
    __shared__ float xsh[SQ];
    __shared__ float part[3][DMD];
    xsh[tid] = x[(b * SQ + tid) * NV + n];
    __syncthreads();
    float acc = 0.f;
    const float* W = W_emb + (sc * 128) * DMD + t;
#pragma unroll 8
    for (int s = 0; s < 128; ++s) acc = fmaf(xsh[sc * 128 + s], W[s * DMD], acc);
    if (sc) part[sc - 1][t] = acc;
    __syncthreads();
    if (sc == 0)
        ws[WS_XE + bn * DMD + t] = acc + part[0][t] + part[1][t] + part[2][t] + b_emb[t];
}

// ---------------- merged: period weights (blocks 0,1) + rank-1 vectors (block 2) ----------------
__global__ __launch_bounds__(128) void k_prep(const int* __restrict__ f1p,
                                              const int* __restrict__ f2p,
                                              const float* __restrict__ Wel, const float* __restrict__ bel,
                                              const float* __restrict__ W_start, const float* __restrict__ b_start,
                                              const float* __restrict__ Wq, const float* __restrict__ bq,
                                              const float* __restrict__ Wk, const float* __restrict__ bk,
                                              const float* __restrict__ Wv, const float* __restrict__ bv,
                                              float* __restrict__ ws) {
    int tid = threadIdx.x;
    __shared__ float ct[DMD], st[DMD];
    __shared__ float a2[2];
    __shared__ float A[DMD], C[DMD], BL[DMD];
    if (blockIdx.x < 2) {
        int b = blockIdx.x;
        float ang = (float)tid * 0.04908738521234052f;   // 2*pi/128
        ct[tid] = cosf(ang);
        st[tid] = sinf(ang);
        __syncthreads();
        int k = tid >> 6;
        int n = tid & 63;
        int f = k ? f2p[0] : f1p[0];
        const float* xr = ws + WS_XE + (b * NV + n) * DMD;
        float re = 0.f, im = 0.f;
        for (int t = 0; t < DMD; ++t) {
            int ph = (f * t) & (DMD - 1);
            float v = xr[t];
            re = fmaf(v, ct[ph], re);
            im = fmaf(v, st[ph], im);
        }
        float amp = sqrtf(re * re + im * im);
        for (int off = 32; off > 0; off >>= 1) amp += __shfl_down(amp, off);
        if (n == 0) a2[k] = amp * (1.0f / NV);
        __syncthreads();
        if (tid == 0) {
            float m = fmaxf(a2[0], a2[1]);
            float e0 = expf(a2[0] - m), e1 = expf(a2[1] - m);
            float inv = 1.0f / (e0 + e1);
            ws[WS_PW + b * 2 + 0] = e0 * inv;
            ws[WS_PW + b * 2 + 1] = e1 * inv;
        }
    } else {
        int e = tid;
        float a = 0.f, c = 0.f;
        for (int d = 0; d < DMD; ++d) {
            float w = Wel[e * DMD + d];
            a = fmaf(w, W_start[d], a);
            c = fmaf(w, b_start[d], c);
        }
        A[e] = a;
        C[e] = c + bel[e];
        BL[e] = bel[e];
        __syncthreads();
        float aq = 0, cq = 0, pq = 0, ak = 0, ck = 0, pk = 0, av = 0, cv = 0, pv = 0;
        for (int d = 0; d < DMD; ++d) {
            float Ad = A[d], Cd = C[d], Bd = BL[d];
            float wq = Wq[e * DMD + d], wk = Wk[e * DMD + d], wv = Wv[e * DMD + d];
            aq = fmaf(wq, Ad, aq); cq = fmaf(wq, Cd, cq); pq = fmaf(wq, Bd, pq);
            ak = fmaf(wk, Ad, ak); ck = fmaf(wk, Cd, ck); pk = fmaf(wk, Bd, pk);
            av = fmaf(wv, Ad, av); cv = fmaf(wv, Cd, cv); pv = fmaf(wv, Bd, pv);
        }
        float* V = ws + WS_VEC;
        V[0 * DMD + e] = aq; V[1 * DMD + e] = cq + bq[e]; V[2 * DMD + e] = pq + bq[e];
        V[3 * DMD + e] = ak; V[4 * DMD + e] = ck + bk[e]; V[5 * DMD + e] = pk + bk[e];
        V[6 * DMD + e] = av; V[7 * DMD + e] = cv + bv[e]; V[8 * DMD + e] = pv + bv[e];
    }
}

// ============ attention paths ============

// Rank-1: P == 128 (f == 1)
__device__ __forceinline__ void attn_rank1(int br, float pwv, const float (*Vsh)[4],
                                           const float* xs, float (*obuf)[132], int tid) {
    float xi = xs[tid];
    float t[4], l[4], ax[4];
#pragma unroll
    for (int k = 0; k < 4; ++k) {
        float Aq = Vsh[0][k], Cq = Vsh[1][k], Ak = Vsh[3][k];
        t[k] = CSC * fmaf(xi, Aq, Cq) * Ak;
        l[k] = 0.f; ax[k] = 0.f;
    }
#pragma unroll 4
    for (int j = 0; j < DMD; ++j) {
        float xj = xs[j];
#pragma unroll
        for (int k = 0; k < 4; ++k) {
            float ev = exp2f(t[k] * xj);
            l[k] += ev;
            ax[k] = fmaf(ev, xj, ax[k]);
        }
    }
#pragma unroll
    for (int k = 0; k < 4; ++k) {
        float Av = Vsh[6][k], Cv = Vsh[7][k];
        float o = fmaf(Av, ax[k] / l[k], Cv);
        float val = pwv * o;
        if (br == 0) obuf[k][tid] = val; else obuf[k][tid] += val;
    }
}

// pow2-P register path: P in {32,64}, no padding, 2-coeff scores
template<int PP, int NP>
__device__ __forceinline__ void attn_pow2(int br, float pwv, const float (*Vsh)[4],
                                          const float* xs, float (*obuf)[132], int tid) {
    const int UH = PP / 4;
    int lane4 = tid & 3, i0 = tid >> 2, jb = lane4 * UH;

    float xq[NP][UH], U2[UH];
#pragma unroll
    for (int u = 0; u < UH; ++u) {
        int j = jb + u;
        float s = 0.f;
#pragma unroll
        for (int q = 0; q < NP; ++q) { float xv = xs[q * PP + j]; xq[q][u] = xv; s += xv; }
        U2[u] = s;
    }
    const int NREP = (PP == 64) ? 2 : 1;
#pragma unroll
    for (int rep = 0; rep < NREP; ++rep) {
        int i = i0 + rep * 32;
        float G2[UH];
#pragma unroll
        for (int u = 0; u < UH; ++u) G2[u] = 0.f;
#pragma unroll
        for (int q = 0; q < NP; ++q) {
            float xi = xs[q * PP + i];
#pragma unroll
            for (int u = 0; u < UH; ++u) G2[u] = fmaf(xi, xq[q][u], G2[u]);
        }
        for (int ec = 0; ec < 4; ++ec) {
            float Aq = Vsh[0][ec], Cq = Vsh[1][ec];
            float Ak = Vsh[3][ec];
            float Av = Vsh[6][ec], Cv = Vsh[7][ec];
            float t = CSC * Ak;
            float d1 = t * Aq, d2 = t * Cq;
            float l0 = 0.f, l1 = 0.f;
            float accq[NP];
#pragma unroll
            for (int q = 0; q < NP; ++q) accq[q] = 0.f;
#pragma unroll
            for (int u = 0; u < UH; ++u) {
                float ev = exp2f(fmaf(d1, G2[u], d2 * U2[u]));
                if (u & 1) l1 += ev; else l0 += ev;
#pragma unroll
                for (int q = 0; q < NP; ++q) accq[q] = fmaf(ev, xq[q][u], accq[q]);
            }
            float l = l0 + l1;
            l += __shfl_xor(l, 1); l += __shfl_xor(l, 2);
#pragma unroll
            for (int q = 0; q < NP; ++q) {
                accq[q] += __shfl_xor(accq[q], 1);
                accq[q] += __shfl_xor(accq[q], 2);
            }
            if (lane4 == 0) {
                float li = 1.f / l;
#pragma unroll
                for (int q = 0; q < NP; ++q) {
                    float o = fmaf(Av, accq[q] * li, Cv);
                    float val = pwv * o;
                    int mo = i * NP + q;
                    if (br == 0) obuf[ec][mo] = val; else obuf[ec][mo] += val;
                }
            }
        }
    }
}

// small-P path: P <= 16. Each score computed once (2 slots/thread) -> LDS W; PV thread-per-output.
template<int UB>
__device__ __forceinline__ void attn_small(
    int P, int pn, int r, int Prows, int br, float pwv,
    const float (*Vsh)[4], const float* xs, const float* U, const float* xt,
    float* W, float (*obuf)[132], int tid)
{
    int GP = P + 1;
    int tot = Prows * P;
    unsigned mP = (4096u + (unsigned)P - 1u) / (unsigned)P;     // ceil(4096/P), exact div for n<=255
    unsigned mpn = (4096u + (unsigned)pn - 1u) / (unsigned)pn;  // ceil(4096/pn), exact for n<=127

    // ---- slot 0 (score idx = tid) ----
    bool v0 = (tid < tot);
    int i0 = (int)(((unsigned)tid * mP) >> 12);
    int j0 = tid - i0 * P;
    bool A0 = (i0 < r), c0 = (j0 < r);
    float xtj0 = xt[j0], Uj0 = U[j0];
    float xti0 = A0 ? xt[i0] : 0.f;
    float g0 = 0.f;
    for (int p = 0; p < pn - 1; ++p) g0 = fmaf(xs[p * P + i0], xs[p * P + j0], g0);
    float Gx0 = (A0 && c0) ? fmaf(xti0, xtj0, g0) : g0;
    float Ux0 = (A0 && c0) ? Uj0 + xtj0 : Uj0;
    float Xw0 = (!A0 && c0) ? xtj0 : 0.f;
    float mw0 = c0 ? 1.f : 0.f;
    int wa0 = i0 * GP + j0;

    // ---- slot 1 (score idx = tid + 128) ----
    int idx1 = tid + 128;
    bool v1 = (idx1 < tot);
    int idx1c = v1 ? idx1 : 0;
    int i1 = (int)(((unsigned)idx1c * mP) >> 12);
    int j1 = idx1c - i1 * P;
    bool A1 = (i1 < r), c1 = (j1 < r);
    float xtj1 = xt[j1], Uj1 = U[j1];
    float xti1 = A1 ? xt[i1] : 0.f;
    float g1 = 0.f;
    for (int p = 0; p < pn - 1; ++p) g1 = fmaf(xs[p * P + i1], xs[p * P + j1], g1);
    float Gx1 = (A1 && c1) ? fmaf(xti1, xtj1, g1) : g1;
    float Ux1 = (A1 && c1) ? Uj1 + xtj1 : Uj1;
    float Xw1 = (!A1 && c1) ? xtj1 : 0.f;
    float mw1 = c1 ? 1.f : 0.f;
    int wa1 = i1 * GP + j1;

    // ---- PV assignment: output mo = tid -> (i2 = tid/pn, p2) ----
    int i2 = (int)(((unsigned)tid * mpn) >> 12);
    int p2 = tid - i2 * pn;
    bool lastp = (p2 == pn - 1);
    int row2 = i2 * GP;
    float xsr[UB];
#pragma unroll
    for (int j = 0; j < UB; ++j) {
        int idx = p2 * P + j;
        xsr[j] = (j < P && idx < DMD) ? xs[idx] : 0.f;
    }

    for (int ec = 0; ec < 4; ++ec) {
        float Aq = Vsh[0][ec], Cq = Vsh[1][ec], Pq = Vsh[2][ec];
        float Ak = Vsh[3][ec], Ck = Vsh[4][ec], Pk = Vsh[5][ec];
        float Av = Vsh[6][ec], Cv = Vsh[7][ec], Pv = Vsh[8][ec];
        float t = CSC * Ak;
        float d1 = t * Aq, d2 = t * Cq, d3 = t * Pq;
        float ckpk = CSC * (Ck - Pk);

        if (v0) {
            float aS = A0 ? fmaf(Aq, xti0, Cq) : Pq;
            float S = (ckpk * aS) * mw0;
            S = fmaf(d3, Xw0, S);
            S = fmaf(d2, Ux0, S);
            S = fmaf(d1, Gx0, S);
            W[wa0] = exp2f(S);
        }
        if (v1) {
            float aS = A1 ? fmaf(Aq, xti1, Cq) : Pq;
            float S = (ckpk * aS) * mw1;
            S = fmaf(d3, Xw1, S);
            S = fmaf(d2, Ux1, S);
            S = fmaf(d1, Gx1, S);
            W[wa1] = exp2f(S);
        }
        __syncthreads();
        float l = 0.f, wr = 0.f, ax = 0.f;
#pragma unroll
        for (int j = 0; j < UB; ++j) {
            float w = W[row2 + ((j < P) ? j : 0)];
            w = (j < P) ? w : 0.f;
            l += w;
            wr += (j < r) ? w : 0.f;
            ax = fmaf(w, xsr[j], ax);
        }
        float li = 1.f / l;
        float o;
        if (lastp) { float sl = wr * li; o = fmaf(Av, ax * li, fmaf(Cv, sl, Pv * (1.f - sl))); }
        else       o = fmaf(Av, ax * li, Cv);
        float val = pwv * o;
        if (br == 0) obuf[ec][tid] = val; else obuf[ec][tid] += val;
        __syncthreads();
    }
}

// mid-P path (P in {18,21,25,42}): round-4 register scheme, Vsh coefficients
template<int UH, int NP>
__device__ __forceinline__ void attn_midA(
    int P, int pn, int r, int Prows, int br, float pwv,
    const float (*Vsh)[4], const float* xs, const float* U,
    const float* xt, float (*obuf)[132], int tid)
{
    int lane4 = tid & 3;
    int i0 = tid >> 2;
    int jb = lane4 * UH;

    float Ur[UH], xtr[UH], xq0[UH], xq1[UH];
#pragma unroll
    for (int u = 0; u < UH; ++u) {
        int j = jb + u, jc = (j < P) ? j : 0;
        Ur[u] = U[jc];
        xtr[u] = xt[jc];
        xq0[u] = (j < DMD) ? xs[j] : 0.f;
        int i1x = P + j;
        xq1[u] = (i1x < DMD) ? xs[i1x] : 0.f;
    }
    int nrep = (Prows > 32) ? 2 : 1;
    for (int rep = 0; rep < nrep; ++rep) {
        int i = i0 + rep * 32;
        bool rowact = (i < Prows);
        int ic = rowact ? i : 0;
        float xtic = xt[ic];
        bool rowvalid = (ic < r);
        float g[UH];
#pragma unroll
        for (int u = 0; u < UH; ++u) g[u] = 0.f;
        for (int p = 0; p < pn - 1; ++p) {
            float xi = xs[p * P + ic];
#pragma unroll
            for (int u = 0; u < UH; ++u) {
                int j = jb + u, jc = (j < P) ? j : 0;
                g[u] = fmaf(xi, xs[p * P + jc], g[u]);
            }
        }
        for (int ec = 0; ec < 4; ++ec) {
            float Aq = Vsh[0][ec], Cq = Vsh[1][ec], Pq = Vsh[2][ec];
            float Ak = Vsh[3][ec], Ck = Vsh[4][ec], Pk = Vsh[5][ec];
            float Av = Vsh[6][ec], Cv = Vsh[7][ec], Pv = Vsh[8][ec];
            float c1 = CSC * Aq * Ak, c3 = CSC * Cq * Ak;
            float asi = CSC * (rowvalid ? fmaf(xtic, Aq, Cq) : Pq);

            float l0 = 0.f, l1 = 0.f, w0 = 0.f, w1 = 0.f;
            float accq[NP];
#pragma unroll
            for (int q = 0; q < NP; ++q) accq[q] = 0.f;
#pragma unroll
            for (int u = 0; u < UH; ++u) {
                int j = jb + u;
                float bK = (j < r) ? fmaf(xtr[u], Ak, Ck) : Pk;
                float S = fmaf(asi, bK, fmaf(c3, Ur[u], c1 * g[u]));
                float ev = exp2f(S);
                ev = (j < P) ? ev : 0.f;
                if (u & 1) l1 += ev; else l0 += ev;
                float evr = (j < r) ? ev : 0.f;
                if (u & 1) w1 += evr; else w0 += evr;
                accq[0] = fmaf(ev, xq0[u], accq[0]);
                if (NP >= 2) accq[1] = fmaf(ev, xq1[u], accq[1]);
#pragma unroll
                for (int q = 2; q < NP; ++q) {
                    int idx = q * P + j;
                    float xv = (idx < DMD) ? xs[idx] : 0.f;
                    accq[q] = fmaf(ev, xv, accq[q]);
                }
            }
            float l = l0 + l1, wr = w0 + w1;
            l += __shfl_xor(l, 1);  l += __shfl_xor(l, 2);
            wr += __shfl_xor(wr, 1); wr += __shfl_xor(wr, 2);
#pragma unroll
            for (int q = 0; q < NP; ++q) {
                if (q < pn) {
                    accq[q] += __shfl_xor(accq[q], 1);
                    accq[q] += __shfl_xor(accq[q], 2);
                }
            }
            if (lane4 == 0 && rowact) {
                float li = 1.f / l;
#pragma unroll
                for (int q = 0; q < NP; ++q) {
                    if (q < pn) {
                        int mo = i * pn + q;
                        if (mo < DMD) {
                            float o;
                            if (q == pn - 1) {
                                float sl = wr * li;
                                o = fmaf(Av, accq[q] * li, fmaf(Cv, sl, Pv * (1.f - sl)));
                            } else {
                                o = fmaf(Av, accq[q] * li, Cv);
                            }
                            float val = pwv * o;
                            if (br == 0) obuf[ec][mo] = val;
                            else         obuf[ec][mo] += val;
                        }
                    }
                }
            }
        }
    }
}

__global__ __launch_bounds__(128) void k_attn(const int* __restrict__ f1p,
                                              const int* __restrict__ f2p,
                                              float* __restrict__ ws) {
    int bn = blockIdx.y, b = bn >> 6;
    int e0 = blockIdx.x * 4;           // 32 chunks of 4 e's
    int tid = threadIdx.x;

    __shared__ float xs[DMD], U[64], xt[64];
    __shared__ float Vsh[9][4];
    __shared__ float W[288];
    __shared__ float obuf[4][132];

    xs[tid] = ws[WS_XE + bn * DMD + tid];
    if (tid < 36) Vsh[tid >> 2][tid & 3] = ws[WS_VEC + (tid >> 2) * DMD + e0 + (tid & 3)];
    int fv0 = f1p[0], fv1 = f2p[0];
    float pw0 = ws[WS_PW + b * 2 + 0];
    float pw1 = ws[WS_PW + b * 2 + 1];
    __syncthreads();

    for (int br = 0; br < 2; ++br) {
        int f = br ? fv1 : fv0;
        float pwv = br ? pw1 : pw0;
        int P = DMD / f;
        int pn = (DMD + P - 1) / P;
        int r = DMD - (pn - 1) * P;
        int Prows = (DMD + pn - 1) / pn;

        if (br == 1) __syncthreads();

        if (P == DMD) {
            attn_rank1(br, pwv, Vsh, xs, obuf, tid);
        } else {
            if (tid < P) {
                float s = 0.f;
                for (int p = 0; p < pn - 1; ++p) s += xs[p * P + tid];
                U[tid] = s;
                xt[tid] = (tid < r) ? xs[(pn - 1) * P + tid] : 0.f;
            }
            __syncthreads();
            if (P <= 4)       attn_small<4>(P, pn, r, Prows, br, pwv, Vsh, xs, U, xt, W, obuf, tid);
            else if (P <= 8)  attn_small<8>(P, pn, r, Prows, br, pwv, Vsh, xs, U, xt, W, obuf, tid);
            else if (P <= 16) attn_small<16>(P, pn, r, Prows, br, pwv, Vsh, xs, U, xt, W, obuf, tid);
            else if (P == 64) attn_pow2<64, 2>(br, pwv, Vsh, xs, obuf, tid);
            else if (P == 32) attn_pow2<32, 4>(br, pwv, Vsh, xs, obuf, tid);
            else if (P > 32)  attn_midA<16, 4>(P, pn, r, Prows, br, pwv, Vsh, xs, U, xt, obuf, tid);  // P=42
            else              attn_midA<8, 8>(P, pn, r, Prows, br, pwv, Vsh, xs, U, xt, obuf, tid);   // 18,21,25
        }
    }
    __syncthreads();
    for (int ec = 0; ec < 4; ++ec)
        ws[WS_OB + (bn * DMD + e0 + ec) * DMD + tid] = obuf[ec][tid];
}

// ---------------- out[bn][e][h] = sum_m ob[bn][e][m]*Wo[h][m] + bo[h], m-chunked ----------------
__global__ __launch_bounds__(256) void k_out(const float* __restrict__ Wo,
                                             const float* __restrict__ bo,
                                             const float* __restrict__ ws,
                                             float* __restrict__ out) {
    int blk = blockIdx.x;          // 256 = 64 bn-pairs * 4 e-quarters
    int bn0 = (blk >> 2) * 2;
    int e0  = (blk & 3) * 32;
    int tid = threadIdx.x;
    __shared__ __align__(16) float WTc[32 * 132];    // [mm][h]
    __shared__ __align__(16) float oT[2][32][36];    // [bnl][mm][e]
    int hg = tid & 31, eg = tid >> 5, h0 = hg * 4;

    float acc[2][4][4];
#pragma unroll
    for (int a = 0; a < 2; ++a)
#pragma unroll
        for (int c = 0; c < 4; ++c)
#pragma unroll
            for (int d = 0; d < 4; ++d) acc[a][c][d] = 0.f;

    for (int mc = 0; mc < 4; ++mc) {
        int m0 = mc * 32;
        __syncthreads();
        for (int idx = tid; idx < 4096; idx += 256) {
            int h = idx >> 5, mm = idx & 31;
            WTc[mm * 132 + h] = Wo[h * DMD + m0 + mm];
        }
        for (int idx = tid; idx < 2048; idx += 256) {
            int bnl = idx >> 10, rem = idx & 1023, e = rem >> 5, mm = rem & 31;
            oT[bnl][mm][e] = ws[WS_OB + ((bn0 + bnl) * DMD + e0 + e) * DMD + m0 + mm];
        }
        __syncthreads();
#pragma unroll 4
        for (int mm = 0; mm < 32; ++mm) {
            const float4 wv = *reinterpret_cast<const float4*>(&WTc[mm * 132 + h0]);
            const float4 q0 = *reinterpret_cast<const float4*>(&oT[0][mm][eg * 4]);
            const float4 q1 = *reinterpret_cast<const float4*>(&oT[1][mm][eg * 4]);
            float ae[2][4] = {{q0.x, q0.y, q0.z, q0.w}, {q1.x, q1.y, q1.z, q1.w}};
#pragma unroll
            for (int bnl = 0; bnl < 2; ++bnl) {
#pragma unroll
                for (int el = 0; el < 4; ++el) {
                    float a = ae[bnl][el];
                    acc[bnl][el][0] = fmaf(a, wv.x, acc[bnl][el][0]);
                    acc[bnl][el][1] = fmaf(a, wv.y, acc[bnl][el][1]);
                    acc[bnl][el][2] = fmaf(a, wv.z, acc[bnl][el][2]);
                    acc[bnl][el][3] = fmaf(a, wv.w, acc[bnl][el][3]);
                }
            }
        }
    }
    const float4 bov = *reinterpret_cast<const float4*>(&bo[h0]);
#pragma unroll
    for (int bnl = 0; bnl < 2; ++bnl) {
#pragma unroll
        for (int el = 0; el < 4; ++el) {
            float4 res = { acc[bnl][el][0] + bov.x, acc[bnl][el][1] + bov.y,
                           acc[bnl][el][2] + bov.z, acc[bnl][el][3] + bov.w };
            int e = e0 + eg * 4 + el;
            *reinterpret_cast<float4*>(&out[((bn0 + bnl) * DMD + e) * DMD + h0]) = res;
        }
    }
}

extern "C" void kernel_launch(void* const* d_in, const int* in_sizes, int n_in,
                              void* d_out, int out_size, void* d_ws, size_t ws_size,
                              hipStream_t stream) {
    const float* x       = (const float*)d_in[0];
    const float* W_emb   = (const float*)d_in[1];
    const float* b_emb   = (const float*)d_in[2];
    const float* W_start = (const float*)d_in[3];
    const float* b_start = (const float*)d_in[4];
    const float* Wel     = (const float*)d_in[5];
    const float* bel     = (const float*)d_in[6];
    const float* Wq      = (const float*)d_in[7];
    const float* bq      = (const float*)d_in[8];
    const float* Wk      = (const float*)d_in[9];
    const float* bk      = (const float*)d_in[10];
    const float* Wv      = (const float*)d_in[11];
    const float* bv      = (const float*)d_in[12];
    const float* Wo      = (const float*)d_in[13];
    const float* bo      = (const float*)d_in[14];
    const int*   f1p     = (const int*)d_in[15];
    const int*   f2p     = (const int*)d_in[16];
    float* ws  = (float*)d_ws;
    float* out = (float*)d_out;

    k_xe<<<NBN, 512, 0, stream>>>(x, W_emb, b_emb, ws);
    k_prep<<<3, 128, 0, stream>>>(f1p, f2p, Wel, bel, W_start, b_start,
                                  Wq, bq, Wk, bk, Wv, bv, ws);
    k_attn<<<dim3(32, NBN), 128, 0, stream>>>(f1p, f2p, ws);
    k_out<<<256, 256, 0, stream>>>(Wo, bo, ws, out);
}